// Round 5
// baseline (1547.817 us; speedup 1.0000x reference)
//
#include <hip/hip_runtime.h>
#include <math.h>

// SparseCoding, round 5.
// vs R4 (367 us): cut per-iter dead time.
//  - 2 barriers/iter (was 4): Q-partial computed from unreduced pacc x plain coef
//    copy (s_cf2) so the loss shuffle-reduce shares the K-reduce barrier; the
//    convergence decision is consumed before the mid barrier.
//  - global loss sync off the critical path: tid64 consumes iter-(it-1) at the top
//    of iter it (posted one full iter ago -> ~zero spin, hidden by SIMD partner
//    wave); tid0 posts iter-it partials with a release atomic (no __threadfence).
//  - fp32 wave-reduce of loss partials; skip self-slice in K-reduction.
#define NB     256
#define NF     128
#define FT     1024
#define NW     63
#define TORIG  256
#define MAXIT  48     // >= n_iter; sizes sync buffers
#define RPB    8      // batch rows per block
#define NBLK   4      // blocks per window
#define GRID   (NW * NBLK)   // 252 blocks; all co-resident at 1 block/CU

// swizzled coef layout: k = 32s + 4m + u, row b  ->  addr = s*SW_S + m*SW_M + b*4 + u
#define SW_S 292
#define SW_M 36
#define SW_SZ (7*SW_S + 7*SW_M + 7*4 + 4)   // 2328 floats

__device__ __forceinline__ float rl(float v, int lane) {
    return __uint_as_float((unsigned)__builtin_amdgcn_readlane((int)__float_as_uint(v), lane));
}

__global__ __launch_bounds__(512, 2) void window_kernel(
    const float* __restrict__ spec,
    const float* __restrict__ basis,
    float* __restrict__ G,               // ws: 256x256
    const int* __restrict__ p_niter,
    const int* __restrict__ p_pad,
    const int* __restrict__ p_stride,
    double* __restrict__ sxbuf,          // [NW][NBLK]
    double* __restrict__ gpart,          // [MAXIT][NW][NBLK][2]
    unsigned int* __restrict__ gcnt,     // [MAXIT*NW] iter counters + [MAXIT*NW]=gbar (memset 0)
    float* __restrict__ out)             // (32,256,63)
{
    __shared__ float  s_part[RPB * RPB * 64 * 4];  // 64 KB  K-reduction exchange
    __shared__ float  s_xn[RPB * FT];              // 32 KB  normalized x
    __shared__ float  s_cf[SW_SZ];                 // 9.3 KB swizzled coef (GEMM operand)
    __shared__ float  s_cf2[RPB][NB];              // 8 KB   plain coef (loss operand)
    __shared__ float  s_gred[2][NB];               // Gram 2-way j-reduce
    __shared__ float  s_mn[RPB], s_rng[RPB];
    __shared__ float  s_red[8][2];
    __shared__ int    s_stop;

    const int bid    = blockIdx.x;
    const int w      = bid >> 2;
    const int q      = bid & 3;
    const int tid    = threadIdx.x;
    const int ks     = tid >> 6;      // wave id: K-slice [32ks,32ks+32) AND local row ks
    const int kg     = tid & 63;      // lane: output cols 4kg..4kg+3
    const int n_iter = p_niter[0];
    const int t0     = w * p_stride[0] - p_pad[0];
    unsigned int* gbar = gcnt + MAXIT * NW;

    // ================= fused Gram: block bid computes G row(s) r =================
    for (int r = bid; r < NB; r += GRID) {
        const int c = tid & 255, jh = tid >> 8;
        float acc = 0.f;
        const float* bp = basis + (size_t)(jh * 512) * NB;
        #pragma unroll 16
        for (int j = 0; j < 512; ++j)
            acc = fmaf(bp[j * NB + r], bp[j * NB + c], acc);
        s_gred[jh][c] = acc;
        __syncthreads();
        if (jh == 0) G[(size_t)r * NB + c] = s_gred[0][c] + s_gred[1][c];
        __syncthreads();
    }
    __threadfence();               // every wave: release its own G stores
    __syncthreads();
    if (tid == 0) atomicAdd(gbar, 1u);

    // ================= stage raw window, min/max, normalize ======================
    #pragma unroll
    for (int i = 0; i < 16; ++i) {
        const int e = i * 512 + tid;
        const int b = e >> 10, jj = e & 1023;
        const int f = jj >> 3, t = jj & 7, tq = t0 + t;
        s_xn[b * FT + jj] = (tq >= 0 && tq < TORIG)
            ? spec[((size_t)(q * RPB + b) * NF + f) * TORIG + tq] : 0.f;
    }
    __syncthreads();
    {   // wave ks scans row ks
        float mn = __builtin_inff(), mx = -__builtin_inff();
        #pragma unroll
        for (int i = 0; i < 16; ++i) {
            const float v = s_xn[ks * FT + i * 64 + kg];
            mn = fminf(mn, v); mx = fmaxf(mx, v);
        }
        #pragma unroll
        for (int off = 32; off; off >>= 1) {
            mn = fminf(mn, __shfl_down(mn, off));
            mx = fmaxf(mx, __shfl_down(mx, off));
        }
        if (kg == 0) { s_mn[ks] = mn; s_rng[ks] = mx - mn; }
    }
    __syncthreads();
    double sx2p = 0.0;
    #pragma unroll
    for (int i = 0; i < 16; ++i) {
        const int e = i * 512 + tid;
        const int b = e >> 10, jj = e & 1023;
        const float v = (s_xn[b * FT + jj] - s_mn[b]) / s_rng[b];   // exact div, matches ref
        s_xn[b * FT + jj] = v;
        sx2p += (double)v * (double)v;
    }
    #pragma unroll
    for (int off = 32; off; off >>= 1) sx2p += __shfl_down(sx2p, off);
    if (kg == 0) s_red[ks][0] = (float)0.f;        // placeholder; sx via s_part trick below
    __shared__ double s_dred[8];
    if (kg == 0) s_dred[ks] = sx2p;
    __syncthreads();                       // s_xn normalized + s_dred ready
    if (tid == 0) {
        double s = 0.0;
        #pragma unroll
        for (int i = 0; i < 8; ++i) s += s_dred[i];
        sxbuf[w * NBLK + q] = s;           // released by the it=0 post (release atomic)
    }

    // ================= xB = xnorm @ basis (K-split partials + LDS reduce) ========
    float xbp[RPB][4];
    #pragma unroll
    for (int b = 0; b < RPB; ++b)
        #pragma unroll
        for (int j = 0; j < 4; ++j) xbp[b][j] = 0.f;
    for (int i0 = 0; i0 < 128; i0 += 4) {
        const int jj = ks * 128 + i0;
        float4 bv[4];
        #pragma unroll
        for (int t = 0; t < 4; ++t)
            bv[t] = *(const float4*)(basis + (size_t)(jj + t) * NB + 4 * kg);
        #pragma unroll
        for (int b = 0; b < RPB; ++b) {
            const float4 x4 = *(const float4*)&s_xn[b * FT + jj];
            xbp[b][0] = fmaf(x4.x, bv[0].x, fmaf(x4.y, bv[1].x, fmaf(x4.z, bv[2].x, fmaf(x4.w, bv[3].x, xbp[b][0]))));
            xbp[b][1] = fmaf(x4.x, bv[0].y, fmaf(x4.y, bv[1].y, fmaf(x4.z, bv[2].y, fmaf(x4.w, bv[3].y, xbp[b][1]))));
            xbp[b][2] = fmaf(x4.x, bv[0].z, fmaf(x4.y, bv[1].z, fmaf(x4.z, bv[2].z, fmaf(x4.w, bv[3].z, xbp[b][2]))));
            xbp[b][3] = fmaf(x4.x, bv[0].w, fmaf(x4.y, bv[1].w, fmaf(x4.z, bv[2].w, fmaf(x4.w, bv[3].w, xbp[b][3]))));
        }
    }
    #pragma unroll
    for (int b = 0; b < RPB; ++b)
        *(float4*)&s_part[((ks * RPB + b) * 64 + kg) * 4] =
            make_float4(xbp[b][0], xbp[b][1], xbp[b][2], xbp[b][3]);
    __syncthreads();
    float xB[4] = {0.f, 0.f, 0.f, 0.f};
    #pragma unroll
    for (int k2 = 0; k2 < 8; ++k2) {
        const float4 p4 = *(const float4*)&s_part[((k2 * RPB + ks) * 64 + kg) * 4];
        xB[0] += p4.x; xB[1] += p4.y; xB[2] += p4.z; xB[3] += p4.w;
    }

    // ================= wait for G (tid0 spin), load register fragment ============
    if (tid == 0) {
        while (__hip_atomic_load(gbar, __ATOMIC_ACQUIRE, __HIP_MEMORY_SCOPE_AGENT) < (unsigned)GRID)
            __builtin_amdgcn_s_sleep(1);
    }
    __syncthreads();
    float4 g[32];
    #pragma unroll
    for (int kl = 0; kl < 32; ++kl)
        g[kl] = *(const float4*)(G + (size_t)(32 * ks + kl) * NB + 4 * kg);

    // ================= init coef / Adam ==========================================
    const float C0 = 0.5f / 256.f;
    float cf[4] = {C0, C0, C0, C0}, m_[4] = {0, 0, 0, 0}, v_[4] = {0, 0, 0, 0};
    *(float4*)&s_cf[(kg >> 3) * SW_S + (kg & 7) * SW_M + ks * 4] = make_float4(C0, C0, C0, C0);
    *(float4*)&s_cf2[ks][4 * kg] = make_float4(C0, C0, C0, C0);
    if (tid == 0) s_stop = 0;
    float b1p = 1.f, b2p = 1.f;
    float old_loss = 1e-10f;    // tid64's loss chain
    double sxtot = 0.0;         // tid64 only
    const float c1 = 2.f / 32768.f, c2 = 0.2f / 8192.f;

    for (int it = 0; it < n_iter; ++it) {
        __syncthreads();        // TOP: s_cf/s_cf2 writes visible; s_part free

        // ---- tid64 (wave1 lane0): consume iter-(it-1) decision (posted last iter) ----
        if (tid == 64) {
            int stop = 0;
            if (it > 0) {
                const size_t pbm = ((size_t)(it - 1) * NW + w) * NBLK;
                while (__hip_atomic_load(&gcnt[(it - 1) * NW + w], __ATOMIC_ACQUIRE,
                                         __HIP_MEMORY_SCOPE_AGENT) < (unsigned)NBLK)
                    __builtin_amdgcn_s_sleep(1);
                double Qt = 0.0, Rt = 0.0;
                #pragma unroll
                for (int i = 0; i < NBLK; ++i) {
                    Qt += gpart[(pbm + i) * 2 + 0];
                    Rt += gpart[(pbm + i) * 2 + 1];
                }
                if (it == 1)
                    sxtot = sxbuf[w * NBLK + 0] + sxbuf[w * NBLK + 1] +
                            sxbuf[w * NBLK + 2] + sxbuf[w * NBLK + 3];
                const float loss = (float)((Qt + sxtot) / 32768.0 + 0.2 * (Rt / 8192.0));
                const float stat = fabsf(old_loss - loss) / old_loss;
                old_loss = loss;
                stop = (stat < 1e-3f) ? 1 : 0;
            }
            s_stop = stop;
        }

        // ---- GEMM: one ds_read_b128 + readlane broadcasts, K-slice partials ----
        const float4 c4 = *(const float4*)&s_cf[ks * SW_S + (kg >> 3) * SW_M + (kg & 7) * 4];
        float pacc[RPB][4];
        #pragma unroll
        for (int b = 0; b < RPB; ++b)
            #pragma unroll
            for (int j = 0; j < 4; ++j) pacc[b][j] = 0.f;
        #pragma unroll
        for (int m = 0; m < 8; ++m) {
            const float4 ga = g[4 * m + 0], gb = g[4 * m + 1];
            const float4 gc = g[4 * m + 2], gd = g[4 * m + 3];
            #pragma unroll
            for (int b = 0; b < RPB; ++b) {
                const int L = m * 8 + b;     // lane holding coef[b][32ks+4m..+3]
                const float cx = rl(c4.x, L), cy = rl(c4.y, L);
                const float cz = rl(c4.z, L), cw = rl(c4.w, L);
                pacc[b][0] = fmaf(cx, ga.x, fmaf(cy, gb.x, fmaf(cz, gc.x, fmaf(cw, gd.x, pacc[b][0]))));
                pacc[b][1] = fmaf(cx, ga.y, fmaf(cy, gb.y, fmaf(cz, gc.y, fmaf(cw, gd.y, pacc[b][1]))));
                pacc[b][2] = fmaf(cx, ga.z, fmaf(cy, gb.z, fmaf(cz, gc.z, fmaf(cw, gd.z, pacc[b][2]))));
                pacc[b][3] = fmaf(cx, ga.w, fmaf(cy, gb.w, fmaf(cz, gc.w, fmaf(cw, gd.w, pacc[b][3]))));
            }
        }

        // ---- post K-slice partials (skip own slice), fire-and-forget ----
        #pragma unroll
        for (int b = 0; b < RPB; ++b)
            if (b != ks)
                *(float4*)&s_part[((ks * RPB + b) * 64 + kg) * 4] =
                    make_float4(pacc[b][0], pacc[b][1], pacc[b][2], pacc[b][3]);

        // ---- loss partials from UNREDUCED pacc x plain coef + own cf terms (fp32) ----
        float qc = 0.f, rr = 0.f;
        #pragma unroll
        for (int b = 0; b < RPB; ++b) {
            const float4 cc = *(const float4*)&s_cf2[b][4 * kg];
            qc += pacc[b][0] * cc.x + pacc[b][1] * cc.y +
                  pacc[b][2] * cc.z + pacc[b][3] * cc.w;
        }
        #pragma unroll
        for (int j = 0; j < 4; ++j) {
            qc -= 2.f * cf[j] * xB[j];
            rr += fabsf(cf[j]);
        }
        #pragma unroll
        for (int off = 32; off; off >>= 1) {
            qc += __shfl_down(qc, off);
            rr += __shfl_down(rr, off);
        }
        if (kg == 0) { s_red[ks][0] = qc; s_red[ks][1] = rr; }

        __syncthreads();        // MID: s_part + s_red + s_stop visible

        const int stop = s_stop;
        if (stop) break;        // conv(it-1) gates update(it) — matches reference

        // ---- K-reduction (own slice from registers) ----
        float a4[4] = {pacc[ks][0], pacc[ks][1], pacc[ks][2], pacc[ks][3]};
        #pragma unroll
        for (int k2 = 0; k2 < 8; ++k2)
            if (k2 != ks) {
                const float4 p4 = *(const float4*)&s_part[((k2 * RPB + ks) * 64 + kg) * 4];
                a4[0] += p4.x; a4[1] += p4.y; a4[2] += p4.z; a4[3] += p4.w;
            }

        // ---- Adam update ----
        b1p *= 0.9f; b2p *= 0.999f;
        const float bc1 = 1.f - b1p, bc2 = 1.f - b2p;
        #pragma unroll
        for (int j = 0; j < 4; ++j) {
            const float c_ = cf[j];
            const float sgn = (c_ > 0.f) ? 1.f : ((c_ < 0.f) ? -1.f : 0.f);
            const float gg = c1 * (a4[j] - xB[j]) + c2 * sgn;
            m_[j] = 0.9f * m_[j] + 0.1f * gg;
            v_[j] = 0.999f * v_[j] + 0.001f * gg * gg;
            cf[j] = c_ - 1e-3f * (m_[j] / bc1) / (sqrtf(v_[j] / bc2) + 1e-8f);
        }
        *(float4*)&s_cf[(kg >> 3) * SW_S + (kg & 7) * SW_M + ks * 4] =
            make_float4(cf[0], cf[1], cf[2], cf[3]);
        *(float4*)&s_cf2[ks][4 * kg] = make_float4(cf[0], cf[1], cf[2], cf[3]);

        // ---- tid0: post iter-it partials (release atomic; consumed next iter) ----
        if (tid == 0) {
            float Q = 0.f, R = 0.f;
            #pragma unroll
            for (int i = 0; i < 8; ++i) { Q += s_red[i][0]; R += s_red[i][1]; }
            const size_t pb = ((size_t)it * NW + w) * NBLK;
            gpart[(pb + q) * 2 + 0] = (double)Q;
            gpart[(pb + q) * 2 + 1] = (double)R;
            __hip_atomic_fetch_add(&gcnt[it * NW + w], 1u,
                                   __ATOMIC_RELEASE, __HIP_MEMORY_SCOPE_AGENT);
        }
    }

    // ---- out[b][k][w], b = q*8+ks, k = 4kg+j ----
    #pragma unroll
    for (int j = 0; j < 4; ++j)
        out[((size_t)(q * RPB + ks) * NB + 4 * kg + j) * NW + w] = cf[j];
}

// ---------------------------------------------------------------------------
extern "C" void kernel_launch(void* const* d_in, const int* in_sizes, int n_in,
                              void* d_out, int out_size, void* d_ws, size_t ws_size,
                              hipStream_t stream)
{
    const float* spec   = (const float*)d_in[0];
    const float* basis  = (const float*)d_in[1];
    const int* p_niter  = (const int*)d_in[2];
    const int* p_pad    = (const int*)d_in[3];
    const int* p_stride = (const int*)d_in[4];
    float* out = (float*)d_out;

    char* ws = (char*)d_ws;
    float*        G     = (float*)ws;                                   // 256 KB
    double*       sxbuf = (double*)(ws + 262144);                       // 2016 B (pad 4 KB)
    double*       gpart = (double*)(ws + 262144 + 4096);                // 193536 B
    unsigned int* gcnt  = (unsigned int*)(ws + 262144 + 4096 + 193536); // (MAXIT*NW+1)*4

    hipMemsetAsync(gcnt, 0, (MAXIT * NW + 1) * sizeof(unsigned int), stream);
    window_kernel<<<dim3(GRID), dim3(512), 0, stream>>>(
        spec, basis, G, p_niter, p_pad, p_stride, sxbuf, gpart, gcnt, out);
}

// Round 6
// 370.999 us; speedup vs baseline: 4.1720x; 4.1720x over previous
//
#include <hip/hip_runtime.h>
#include <math.h>

// SparseCoding, round 6.
// vs R5 (1548 us, spill regression): keep the 2-barrier + deferred-global-sync
// structure but make pacc fully DEAD at the MID barrier (R5 kept pacc[ks] live
// across it -> 32-reg liveness on top of the 128-reg G fragment -> scratch
// spills, 730 MB FETCH). a4 is rebuilt entirely from s_part like R4.
//  - tid64 consumes iter-(it-1) loss totals at the top of iter it (posted a full
//    iteration earlier -> ~zero spin, hidden by the SIMD partner wave).
//  - tid0 posts iter-it partials with a release atomic, fire-and-forget.
//  - loss Q-partial computed pre-barrier from unreduced pacc x plain coef (s_cf2).
#define NB     256
#define NF     128
#define FT     1024
#define NW     63
#define TORIG  256
#define MAXIT  48     // >= n_iter; sizes sync buffers
#define RPB    8      // batch rows per block
#define NBLK   4      // blocks per window
#define GRID   (NW * NBLK)   // 252 blocks; all co-resident at 1 block/CU

// swizzled coef layout: k = 32s + 4m + u, row b  ->  addr = s*SW_S + m*SW_M + b*4 + u
// injectivity: SW_S(292) > max(m*36+b*4+u)=283 ; SW_M(36) > 31 ; 4 > 3
#define SW_S 292
#define SW_M 36
#define SW_SZ (7*SW_S + 7*SW_M + 7*4 + 4)   // 2328 floats

__device__ __forceinline__ float rl(float v, int lane) {
    return __uint_as_float((unsigned)__builtin_amdgcn_readlane((int)__float_as_uint(v), lane));
}

__global__ __launch_bounds__(512, 2) void window_kernel(
    const float* __restrict__ spec,
    const float* __restrict__ basis,
    float* __restrict__ G,               // ws: 256x256
    const int* __restrict__ p_niter,
    const int* __restrict__ p_pad,
    const int* __restrict__ p_stride,
    double* __restrict__ sxbuf,          // [NW][NBLK]
    double* __restrict__ gpart,          // [MAXIT][NW][NBLK][2]
    unsigned int* __restrict__ gcnt,     // [MAXIT*NW] iter counters + [MAXIT*NW]=gbar (memset 0)
    float* __restrict__ out)             // (32,256,63)
{
    __shared__ float  s_part[RPB * RPB * 64 * 4];  // 64 KB  K-reduction exchange
    __shared__ float  s_xn[RPB * FT];              // 32 KB  normalized x
    __shared__ float  s_cf[SW_SZ];                 // 9.3 KB swizzled coef (GEMM operand)
    __shared__ float  s_cf2[RPB][NB];              // 8 KB   plain coef (loss operand)
    __shared__ float  s_gred[2][NB];               // Gram 2-way j-reduce
    __shared__ float  s_mn[RPB], s_rng[RPB];
    __shared__ float  s_red[8][2];
    __shared__ double s_dred[8];
    __shared__ int    s_stop;

    const int bid    = blockIdx.x;
    const int w      = bid >> 2;
    const int q      = bid & 3;
    const int tid    = threadIdx.x;
    const int ks     = tid >> 6;      // wave id: K-slice [32ks,32ks+32) AND local row ks
    const int kg     = tid & 63;      // lane: output cols 4kg..4kg+3
    const int n_iter = p_niter[0];
    const int t0     = w * p_stride[0] - p_pad[0];
    unsigned int* gbar = gcnt + MAXIT * NW;

    // ================= fused Gram: block bid computes G row(s) r =================
    for (int r = bid; r < NB; r += GRID) {
        const int c = tid & 255, jh = tid >> 8;
        float acc = 0.f;
        const float* bp = basis + (size_t)(jh * 512) * NB;
        #pragma unroll 16
        for (int j = 0; j < 512; ++j)
            acc = fmaf(bp[j * NB + r], bp[j * NB + c], acc);
        s_gred[jh][c] = acc;
        __syncthreads();
        if (jh == 0) G[(size_t)r * NB + c] = s_gred[0][c] + s_gred[1][c];
        __syncthreads();
    }
    __threadfence();               // every wave: release its own G stores
    __syncthreads();
    if (tid == 0) atomicAdd(gbar, 1u);

    // ================= stage raw window, min/max, normalize ======================
    #pragma unroll
    for (int i = 0; i < 16; ++i) {
        const int e = i * 512 + tid;
        const int b = e >> 10, jj = e & 1023;
        const int f = jj >> 3, t = jj & 7, tq = t0 + t;
        s_xn[b * FT + jj] = (tq >= 0 && tq < TORIG)
            ? spec[((size_t)(q * RPB + b) * NF + f) * TORIG + tq] : 0.f;
    }
    __syncthreads();
    {   // wave ks scans row ks
        float mn = __builtin_inff(), mx = -__builtin_inff();
        #pragma unroll
        for (int i = 0; i < 16; ++i) {
            const float v = s_xn[ks * FT + i * 64 + kg];
            mn = fminf(mn, v); mx = fmaxf(mx, v);
        }
        #pragma unroll
        for (int off = 32; off; off >>= 1) {
            mn = fminf(mn, __shfl_down(mn, off));
            mx = fmaxf(mx, __shfl_down(mx, off));
        }
        if (kg == 0) { s_mn[ks] = mn; s_rng[ks] = mx - mn; }
    }
    __syncthreads();
    double sx2p = 0.0;
    #pragma unroll
    for (int i = 0; i < 16; ++i) {
        const int e = i * 512 + tid;
        const int b = e >> 10, jj = e & 1023;
        const float v = (s_xn[b * FT + jj] - s_mn[b]) / s_rng[b];   // exact div, matches ref
        s_xn[b * FT + jj] = v;
        sx2p += (double)v * (double)v;
    }
    #pragma unroll
    for (int off = 32; off; off >>= 1) sx2p += __shfl_down(sx2p, off);
    if (kg == 0) s_dred[ks] = sx2p;
    __syncthreads();                       // s_xn normalized + s_dred ready
    if (tid == 0) {
        double s = 0.0;
        #pragma unroll
        for (int i = 0; i < 8; ++i) s += s_dred[i];
        sxbuf[w * NBLK + q] = s;           // released by the it=0 post (release atomic)
    }

    // ================= xB = xnorm @ basis (K-split partials + LDS reduce) ========
    float xbp[RPB][4];
    #pragma unroll
    for (int b = 0; b < RPB; ++b)
        #pragma unroll
        for (int j = 0; j < 4; ++j) xbp[b][j] = 0.f;
    for (int i0 = 0; i0 < 128; i0 += 4) {
        const int jj = ks * 128 + i0;
        float4 bv[4];
        #pragma unroll
        for (int t = 0; t < 4; ++t)
            bv[t] = *(const float4*)(basis + (size_t)(jj + t) * NB + 4 * kg);
        #pragma unroll
        for (int b = 0; b < RPB; ++b) {
            const float4 x4 = *(const float4*)&s_xn[b * FT + jj];
            xbp[b][0] = fmaf(x4.x, bv[0].x, fmaf(x4.y, bv[1].x, fmaf(x4.z, bv[2].x, fmaf(x4.w, bv[3].x, xbp[b][0]))));
            xbp[b][1] = fmaf(x4.x, bv[0].y, fmaf(x4.y, bv[1].y, fmaf(x4.z, bv[2].y, fmaf(x4.w, bv[3].y, xbp[b][1]))));
            xbp[b][2] = fmaf(x4.x, bv[0].z, fmaf(x4.y, bv[1].z, fmaf(x4.z, bv[2].z, fmaf(x4.w, bv[3].z, xbp[b][2]))));
            xbp[b][3] = fmaf(x4.x, bv[0].w, fmaf(x4.y, bv[1].w, fmaf(x4.z, bv[2].w, fmaf(x4.w, bv[3].w, xbp[b][3]))));
        }
    }
    #pragma unroll
    for (int b = 0; b < RPB; ++b)
        *(float4*)&s_part[((ks * RPB + b) * 64 + kg) * 4] =
            make_float4(xbp[b][0], xbp[b][1], xbp[b][2], xbp[b][3]);
    __syncthreads();
    float xB[4] = {0.f, 0.f, 0.f, 0.f};
    #pragma unroll
    for (int k2 = 0; k2 < 8; ++k2) {
        const float4 p4 = *(const float4*)&s_part[((k2 * RPB + ks) * 64 + kg) * 4];
        xB[0] += p4.x; xB[1] += p4.y; xB[2] += p4.z; xB[3] += p4.w;
    }

    // ================= wait for G (tid0 spin), load register fragment ============
    if (tid == 0) {
        while (__hip_atomic_load(gbar, __ATOMIC_ACQUIRE, __HIP_MEMORY_SCOPE_AGENT) < (unsigned)GRID)
            __builtin_amdgcn_s_sleep(1);
    }
    __syncthreads();
    float4 g[32];
    #pragma unroll
    for (int kl = 0; kl < 32; ++kl)
        g[kl] = *(const float4*)(G + (size_t)(32 * ks + kl) * NB + 4 * kg);

    // ================= init coef / Adam ==========================================
    const float C0 = 0.5f / 256.f;
    float cf[4] = {C0, C0, C0, C0}, m_[4] = {0, 0, 0, 0}, v_[4] = {0, 0, 0, 0};
    *(float4*)&s_cf[(kg >> 3) * SW_S + (kg & 7) * SW_M + ks * 4] = make_float4(C0, C0, C0, C0);
    *(float4*)&s_cf2[ks][4 * kg] = make_float4(C0, C0, C0, C0);
    if (tid == 0) s_stop = 0;
    float b1p = 1.f, b2p = 1.f;
    float old_loss = 1e-10f;    // tid64's loss chain
    double sxtot = 0.0;         // tid64 only
    const float c1 = 2.f / 32768.f, c2 = 0.2f / 8192.f;

    for (int it = 0; it < n_iter; ++it) {
        __syncthreads();        // TOP: s_cf/s_cf2 writes visible; s_part free

        // ---- tid64 (wave1 lane0): consume iter-(it-1) decision (posted last iter) ----
        if (tid == 64) {
            int stop = 0;
            if (it > 0) {
                const size_t pbm = ((size_t)(it - 1) * NW + w) * NBLK;
                while (__hip_atomic_load(&gcnt[(it - 1) * NW + w], __ATOMIC_ACQUIRE,
                                         __HIP_MEMORY_SCOPE_AGENT) < (unsigned)NBLK)
                    __builtin_amdgcn_s_sleep(1);
                double Qt = 0.0, Rt = 0.0;
                #pragma unroll
                for (int i = 0; i < NBLK; ++i) {
                    Qt += gpart[(pbm + i) * 2 + 0];
                    Rt += gpart[(pbm + i) * 2 + 1];
                }
                if (it == 1)
                    sxtot = sxbuf[w * NBLK + 0] + sxbuf[w * NBLK + 1] +
                            sxbuf[w * NBLK + 2] + sxbuf[w * NBLK + 3];
                const float loss = (float)((Qt + sxtot) / 32768.0 + 0.2 * (Rt / 8192.0));
                const float stat = fabsf(old_loss - loss) / old_loss;
                old_loss = loss;
                stop = (stat < 1e-3f) ? 1 : 0;
            }
            s_stop = stop;
        }

        // ---- GEMM: one ds_read_b128 + readlane broadcasts, K-slice partials ----
        const float4 c4 = *(const float4*)&s_cf[ks * SW_S + (kg >> 3) * SW_M + (kg & 7) * 4];
        float pacc[RPB][4];
        #pragma unroll
        for (int b = 0; b < RPB; ++b)
            #pragma unroll
            for (int j = 0; j < 4; ++j) pacc[b][j] = 0.f;
        #pragma unroll
        for (int m = 0; m < 8; ++m) {
            const float4 ga = g[4 * m + 0], gb = g[4 * m + 1];
            const float4 gc = g[4 * m + 2], gd = g[4 * m + 3];
            #pragma unroll
            for (int b = 0; b < RPB; ++b) {
                const int L = m * 8 + b;     // lane holding coef[b][32ks+4m..+3]
                const float cx = rl(c4.x, L), cy = rl(c4.y, L);
                const float cz = rl(c4.z, L), cw = rl(c4.w, L);
                pacc[b][0] = fmaf(cx, ga.x, fmaf(cy, gb.x, fmaf(cz, gc.x, fmaf(cw, gd.x, pacc[b][0]))));
                pacc[b][1] = fmaf(cx, ga.y, fmaf(cy, gb.y, fmaf(cz, gc.y, fmaf(cw, gd.y, pacc[b][1]))));
                pacc[b][2] = fmaf(cx, ga.z, fmaf(cy, gb.z, fmaf(cz, gc.z, fmaf(cw, gd.z, pacc[b][2]))));
                pacc[b][3] = fmaf(cx, ga.w, fmaf(cy, gb.w, fmaf(cz, gc.w, fmaf(cw, gd.w, pacc[b][3]))));
            }
        }

        // ---- loss partials from UNREDUCED pacc x plain coef + own cf terms (fp32) ----
        float qc = 0.f, rr = 0.f;
        #pragma unroll
        for (int b = 0; b < RPB; ++b) {
            const float4 cc = *(const float4*)&s_cf2[b][4 * kg];
            qc += pacc[b][0] * cc.x + pacc[b][1] * cc.y +
                  pacc[b][2] * cc.z + pacc[b][3] * cc.w;
        }
        #pragma unroll
        for (int j = 0; j < 4; ++j) {
            qc -= 2.f * cf[j] * xB[j];
            rr += fabsf(cf[j]);
        }

        // ---- post ALL K-slice partials (pacc dies HERE, before the barrier) ----
        #pragma unroll
        for (int b = 0; b < RPB; ++b)
            *(float4*)&s_part[((ks * RPB + b) * 64 + kg) * 4] =
                make_float4(pacc[b][0], pacc[b][1], pacc[b][2], pacc[b][3]);

        #pragma unroll
        for (int off = 32; off; off >>= 1) {
            qc += __shfl_down(qc, off);
            rr += __shfl_down(rr, off);
        }
        if (kg == 0) { s_red[ks][0] = qc; s_red[ks][1] = rr; }

        __syncthreads();        // MID: s_part + s_red + s_stop visible

        if (s_stop) break;      // conv(it-1) gates update(it) — matches reference

        // ---- K-reduction entirely from LDS (no register carry across barrier) ----
        float a4[4] = {0.f, 0.f, 0.f, 0.f};
        #pragma unroll
        for (int k2 = 0; k2 < 8; ++k2) {
            const float4 p4 = *(const float4*)&s_part[((k2 * RPB + ks) * 64 + kg) * 4];
            a4[0] += p4.x; a4[1] += p4.y; a4[2] += p4.z; a4[3] += p4.w;
        }

        // ---- Adam update ----
        b1p *= 0.9f; b2p *= 0.999f;
        const float bc1 = 1.f - b1p, bc2 = 1.f - b2p;
        #pragma unroll
        for (int j = 0; j < 4; ++j) {
            const float c_ = cf[j];
            const float sgn = (c_ > 0.f) ? 1.f : ((c_ < 0.f) ? -1.f : 0.f);
            const float gg = c1 * (a4[j] - xB[j]) + c2 * sgn;
            m_[j] = 0.9f * m_[j] + 0.1f * gg;
            v_[j] = 0.999f * v_[j] + 0.001f * gg * gg;
            cf[j] = c_ - 1e-3f * (m_[j] / bc1) / (sqrtf(v_[j] / bc2) + 1e-8f);
        }
        *(float4*)&s_cf[(kg >> 3) * SW_S + (kg & 7) * SW_M + ks * 4] =
            make_float4(cf[0], cf[1], cf[2], cf[3]);
        *(float4*)&s_cf2[ks][4 * kg] = make_float4(cf[0], cf[1], cf[2], cf[3]);

        // ---- tid0: post iter-it partials (release atomic; consumed next iter) ----
        if (tid == 0) {
            float Q = 0.f, R = 0.f;
            #pragma unroll
            for (int i = 0; i < 8; ++i) { Q += s_red[i][0]; R += s_red[i][1]; }
            const size_t pb = ((size_t)it * NW + w) * NBLK;
            gpart[(pb + q) * 2 + 0] = (double)Q;
            gpart[(pb + q) * 2 + 1] = (double)R;
            __hip_atomic_fetch_add(&gcnt[it * NW + w], 1u,
                                   __ATOMIC_RELEASE, __HIP_MEMORY_SCOPE_AGENT);
        }
    }

    // ---- out[b][k][w], b = q*8+ks, k = 4kg+j ----
    #pragma unroll
    for (int j = 0; j < 4; ++j)
        out[((size_t)(q * RPB + ks) * NB + 4 * kg + j) * NW + w] = cf[j];
}

// ---------------------------------------------------------------------------
extern "C" void kernel_launch(void* const* d_in, const int* in_sizes, int n_in,
                              void* d_out, int out_size, void* d_ws, size_t ws_size,
                              hipStream_t stream)
{
    const float* spec   = (const float*)d_in[0];
    const float* basis  = (const float*)d_in[1];
    const int* p_niter  = (const int*)d_in[2];
    const int* p_pad    = (const int*)d_in[3];
    const int* p_stride = (const int*)d_in[4];
    float* out = (float*)d_out;

    char* ws = (char*)d_ws;
    float*        G     = (float*)ws;                                   // 256 KB
    double*       sxbuf = (double*)(ws + 262144);                       // 2016 B (pad 4 KB)
    double*       gpart = (double*)(ws + 262144 + 4096);                // 193536 B
    unsigned int* gcnt  = (unsigned int*)(ws + 262144 + 4096 + 193536); // (MAXIT*NW+1)*4

    hipMemsetAsync(gcnt, 0, (MAXIT * NW + 1) * sizeof(unsigned int), stream);
    window_kernel<<<dim3(GRID), dim3(512), 0, stream>>>(
        spec, basis, G, p_niter, p_pad, p_stride, sxbuf, gpart, gcnt, out);
}

// Round 7
// 342.953 us; speedup vs baseline: 4.5132x; 1.0818x over previous
//
#include <hip/hip_runtime.h>
#include <math.h>

// SparseCoding, round 7.
// vs R6 (371 us): attack the EXPOSED per-iter global sync round-trip.
//  - post loss partials right after MID barrier (before K-reduce/Adam) ->
//    ~1.5-2 us of slack before they are consumed at TOP of the next iter
//    (R6 posted at iter END and consumed at next TOP: zero slack).
//  - XCD-colocation: 256 blocks, swizzled so a window's 4 blocks share
//    bid%8 (same XCD under round-robin dispatch) -> sync stays in one L2.
//    Blocks decoding to w==63 do a Gram row, arrive at gbar, exit.
//  - skip the post on the stop iteration (no consumer).
#define NB     256
#define NF     128
#define FT     1024
#define NW     63
#define TORIG  256
#define MAXIT  48     // >= n_iter; sizes sync buffers
#define RPB    8      // batch rows per block
#define NBLK   4      // blocks per window
#define GRID   256    // 1 block/CU, all co-resident; 4 blocks (w==63) exit early

// swizzled coef layout: k = 32s + 4m + u, row b  ->  addr = s*SW_S + m*SW_M + b*4 + u
// injectivity: SW_S(292) > max(m*36+b*4+u)=283 ; SW_M(36) > 31 ; 4 > 3
#define SW_S 292
#define SW_M 36
#define SW_SZ (7*SW_S + 7*SW_M + 7*4 + 4)   // 2328 floats

__device__ __forceinline__ float rl(float v, int lane) {
    return __uint_as_float((unsigned)__builtin_amdgcn_readlane((int)__float_as_uint(v), lane));
}

__global__ __launch_bounds__(512, 2) void window_kernel(
    const float* __restrict__ spec,
    const float* __restrict__ basis,
    float* __restrict__ G,               // ws: 256x256
    const int* __restrict__ p_niter,
    const int* __restrict__ p_pad,
    const int* __restrict__ p_stride,
    double* __restrict__ sxbuf,          // [NW][NBLK]
    double* __restrict__ gpart,          // [MAXIT][NW][NBLK][2]
    unsigned int* __restrict__ gcnt,     // [MAXIT*NW] iter counters + [MAXIT*NW]=gbar (memset 0)
    float* __restrict__ out)             // (32,256,63)
{
    __shared__ float  s_part[RPB * RPB * 64 * 4];  // 64 KB  K-reduction exchange
    __shared__ float  s_xn[RPB * FT];              // 32 KB  normalized x
    __shared__ float  s_cf[SW_SZ];                 // 9.3 KB swizzled coef (GEMM operand)
    __shared__ float  s_cf2[RPB][NB];              // 8 KB   plain coef (loss operand)
    __shared__ float  s_gred[2][NB];               // Gram 2-way j-reduce
    __shared__ float  s_mn[RPB], s_rng[RPB];
    __shared__ float  s_red[8][2];
    __shared__ double s_dred[8];
    __shared__ int    s_stop;

    const int bid    = blockIdx.x;
    // bid = xcd + 8*(4*slot + q), w = xcd + 8*slot  ->  all 4 blocks of a window
    // share bid%8 (same XCD under round-robin dispatch).
    const int yy     = bid >> 3;
    const int q      = yy & 3;
    const int w      = (bid & 7) + 8 * (yy >> 2);
    const int tid    = threadIdx.x;
    const int ks     = tid >> 6;      // wave id: K-slice [32ks,32ks+32) AND local row ks
    const int kg     = tid & 63;      // lane: output cols 4kg..4kg+3
    const int n_iter = p_niter[0];
    const int t0     = w * p_stride[0] - p_pad[0];
    unsigned int* gbar = gcnt + MAXIT * NW;

    // ================= fused Gram: block bid computes G row bid =================
    {
        const int r = bid;
        const int c = tid & 255, jh = tid >> 8;
        float acc = 0.f;
        const float* bp = basis + (size_t)(jh * 512) * NB;
        #pragma unroll 16
        for (int j = 0; j < 512; ++j)
            acc = fmaf(bp[j * NB + r], bp[j * NB + c], acc);
        s_gred[jh][c] = acc;
        __syncthreads();
        if (jh == 0) G[(size_t)r * NB + c] = s_gred[0][c] + s_gred[1][c];
    }
    __threadfence();               // every wave: release its own G stores
    __syncthreads();
    if (tid == 0) atomicAdd(gbar, 1u);

    if (w >= NW) return;           // helper blocks (w==63 decode) are done

    // ================= stage raw window, min/max, normalize ======================
    #pragma unroll
    for (int i = 0; i < 16; ++i) {
        const int e = i * 512 + tid;
        const int b = e >> 10, jj = e & 1023;
        const int f = jj >> 3, t = jj & 7, tq = t0 + t;
        s_xn[b * FT + jj] = (tq >= 0 && tq < TORIG)
            ? spec[((size_t)(q * RPB + b) * NF + f) * TORIG + tq] : 0.f;
    }
    __syncthreads();
    {   // wave ks scans row ks
        float mn = __builtin_inff(), mx = -__builtin_inff();
        #pragma unroll
        for (int i = 0; i < 16; ++i) {
            const float v = s_xn[ks * FT + i * 64 + kg];
            mn = fminf(mn, v); mx = fmaxf(mx, v);
        }
        #pragma unroll
        for (int off = 32; off; off >>= 1) {
            mn = fminf(mn, __shfl_down(mn, off));
            mx = fmaxf(mx, __shfl_down(mx, off));
        }
        if (kg == 0) { s_mn[ks] = mn; s_rng[ks] = mx - mn; }
    }
    __syncthreads();
    double sx2p = 0.0;
    #pragma unroll
    for (int i = 0; i < 16; ++i) {
        const int e = i * 512 + tid;
        const int b = e >> 10, jj = e & 1023;
        const float v = (s_xn[b * FT + jj] - s_mn[b]) / s_rng[b];   // exact div, matches ref
        s_xn[b * FT + jj] = v;
        sx2p += (double)v * (double)v;
    }
    #pragma unroll
    for (int off = 32; off; off >>= 1) sx2p += __shfl_down(sx2p, off);
    if (kg == 0) s_dred[ks] = sx2p;
    __syncthreads();                       // s_xn normalized + s_dred ready
    if (tid == 0) {
        double s = 0.0;
        #pragma unroll
        for (int i = 0; i < 8; ++i) s += s_dred[i];
        sxbuf[w * NBLK + q] = s;           // released by the it=0 post (release atomic)
    }

    // ================= xB = xnorm @ basis (K-split partials + LDS reduce) ========
    float xbp[RPB][4];
    #pragma unroll
    for (int b = 0; b < RPB; ++b)
        #pragma unroll
        for (int j = 0; j < 4; ++j) xbp[b][j] = 0.f;
    for (int i0 = 0; i0 < 128; i0 += 4) {
        const int jj = ks * 128 + i0;
        float4 bv[4];
        #pragma unroll
        for (int t = 0; t < 4; ++t)
            bv[t] = *(const float4*)(basis + (size_t)(jj + t) * NB + 4 * kg);
        #pragma unroll
        for (int b = 0; b < RPB; ++b) {
            const float4 x4 = *(const float4*)&s_xn[b * FT + jj];
            xbp[b][0] = fmaf(x4.x, bv[0].x, fmaf(x4.y, bv[1].x, fmaf(x4.z, bv[2].x, fmaf(x4.w, bv[3].x, xbp[b][0]))));
            xbp[b][1] = fmaf(x4.x, bv[0].y, fmaf(x4.y, bv[1].y, fmaf(x4.z, bv[2].y, fmaf(x4.w, bv[3].y, xbp[b][1]))));
            xbp[b][2] = fmaf(x4.x, bv[0].z, fmaf(x4.y, bv[1].z, fmaf(x4.z, bv[2].z, fmaf(x4.w, bv[3].z, xbp[b][2]))));
            xbp[b][3] = fmaf(x4.x, bv[0].w, fmaf(x4.y, bv[1].w, fmaf(x4.z, bv[2].w, fmaf(x4.w, bv[3].w, xbp[b][3]))));
        }
    }
    #pragma unroll
    for (int b = 0; b < RPB; ++b)
        *(float4*)&s_part[((ks * RPB + b) * 64 + kg) * 4] =
            make_float4(xbp[b][0], xbp[b][1], xbp[b][2], xbp[b][3]);
    __syncthreads();
    float xB[4] = {0.f, 0.f, 0.f, 0.f};
    #pragma unroll
    for (int k2 = 0; k2 < 8; ++k2) {
        const float4 p4 = *(const float4*)&s_part[((k2 * RPB + ks) * 64 + kg) * 4];
        xB[0] += p4.x; xB[1] += p4.y; xB[2] += p4.z; xB[3] += p4.w;
    }

    // ================= wait for G (tid0 spin), load register fragment ============
    if (tid == 0) {
        while (__hip_atomic_load(gbar, __ATOMIC_ACQUIRE, __HIP_MEMORY_SCOPE_AGENT) < (unsigned)GRID)
            __builtin_amdgcn_s_sleep(1);
    }
    __syncthreads();
    float4 g[32];
    #pragma unroll
    for (int kl = 0; kl < 32; ++kl)
        g[kl] = *(const float4*)(G + (size_t)(32 * ks + kl) * NB + 4 * kg);

    // ================= init coef / Adam ==========================================
    const float C0 = 0.5f / 256.f;
    float cf[4] = {C0, C0, C0, C0}, m_[4] = {0, 0, 0, 0}, v_[4] = {0, 0, 0, 0};
    *(float4*)&s_cf[(kg >> 3) * SW_S + (kg & 7) * SW_M + ks * 4] = make_float4(C0, C0, C0, C0);
    *(float4*)&s_cf2[ks][4 * kg] = make_float4(C0, C0, C0, C0);
    if (tid == 0) s_stop = 0;
    float b1p = 1.f, b2p = 1.f;
    float old_loss = 1e-10f;    // tid64's loss chain
    double sxtot = 0.0;         // tid64 only
    const float c1 = 2.f / 32768.f, c2 = 0.2f / 8192.f;

    for (int it = 0; it < n_iter; ++it) {
        __syncthreads();        // TOP: s_cf/s_cf2 writes visible; s_part free

        // ---- tid64 (wave1 lane0): consume iter-(it-1) decision.
        // Partials were posted just after MID of iter it-1 (one Adam + barrier ago)
        // and live in THIS XCD's L2 (colocated blocks) -> near-zero spin. ----
        if (tid == 64) {
            int stop = 0;
            if (it > 0) {
                const size_t pbm = ((size_t)(it - 1) * NW + w) * NBLK;
                while (__hip_atomic_load(&gcnt[(it - 1) * NW + w], __ATOMIC_ACQUIRE,
                                         __HIP_MEMORY_SCOPE_AGENT) < (unsigned)NBLK)
                    __builtin_amdgcn_s_sleep(1);
                double Qt = 0.0, Rt = 0.0;
                #pragma unroll
                for (int i = 0; i < NBLK; ++i) {
                    Qt += gpart[(pbm + i) * 2 + 0];
                    Rt += gpart[(pbm + i) * 2 + 1];
                }
                if (it == 1)
                    sxtot = sxbuf[w * NBLK + 0] + sxbuf[w * NBLK + 1] +
                            sxbuf[w * NBLK + 2] + sxbuf[w * NBLK + 3];
                const float loss = (float)((Qt + sxtot) / 32768.0 + 0.2 * (Rt / 8192.0));
                const float stat = fabsf(old_loss - loss) / old_loss;
                old_loss = loss;
                stop = (stat < 1e-3f) ? 1 : 0;
            }
            s_stop = stop;
        }

        // ---- GEMM: one ds_read_b128 + readlane broadcasts, K-slice partials ----
        const float4 c4 = *(const float4*)&s_cf[ks * SW_S + (kg >> 3) * SW_M + (kg & 7) * 4];
        float pacc[RPB][4];
        #pragma unroll
        for (int b = 0; b < RPB; ++b)
            #pragma unroll
            for (int j = 0; j < 4; ++j) pacc[b][j] = 0.f;
        #pragma unroll
        for (int m = 0; m < 8; ++m) {
            const float4 ga = g[4 * m + 0], gb = g[4 * m + 1];
            const float4 gc = g[4 * m + 2], gd = g[4 * m + 3];
            #pragma unroll
            for (int b = 0; b < RPB; ++b) {
                const int L = m * 8 + b;     // lane holding coef[b][32ks+4m..+3]
                const float cx = rl(c4.x, L), cy = rl(c4.y, L);
                const float cz = rl(c4.z, L), cw = rl(c4.w, L);
                pacc[b][0] = fmaf(cx, ga.x, fmaf(cy, gb.x, fmaf(cz, gc.x, fmaf(cw, gd.x, pacc[b][0]))));
                pacc[b][1] = fmaf(cx, ga.y, fmaf(cy, gb.y, fmaf(cz, gc.y, fmaf(cw, gd.y, pacc[b][1]))));
                pacc[b][2] = fmaf(cx, ga.z, fmaf(cy, gb.z, fmaf(cz, gc.z, fmaf(cw, gd.z, pacc[b][2]))));
                pacc[b][3] = fmaf(cx, ga.w, fmaf(cy, gb.w, fmaf(cz, gc.w, fmaf(cw, gd.w, pacc[b][3]))));
            }
        }

        // ---- loss partials from UNREDUCED pacc x plain coef + own cf terms (fp32) ----
        float qc = 0.f, rr = 0.f;
        #pragma unroll
        for (int b = 0; b < RPB; ++b) {
            const float4 cc = *(const float4*)&s_cf2[b][4 * kg];
            qc += pacc[b][0] * cc.x + pacc[b][1] * cc.y +
                  pacc[b][2] * cc.z + pacc[b][3] * cc.w;
        }
        #pragma unroll
        for (int j = 0; j < 4; ++j) {
            qc -= 2.f * cf[j] * xB[j];
            rr += fabsf(cf[j]);
        }

        // ---- post ALL K-slice partials (pacc dies HERE, before the barrier) ----
        #pragma unroll
        for (int b = 0; b < RPB; ++b)
            *(float4*)&s_part[((ks * RPB + b) * 64 + kg) * 4] =
                make_float4(pacc[b][0], pacc[b][1], pacc[b][2], pacc[b][3]);

        #pragma unroll
        for (int off = 32; off; off >>= 1) {
            qc += __shfl_down(qc, off);
            rr += __shfl_down(rr, off);
        }
        if (kg == 0) { s_red[ks][0] = qc; s_red[ks][1] = rr; }

        __syncthreads();        // MID: s_part + s_red + s_stop visible

        if (s_stop) break;      // conv(it-1) gates update(it); no post needed when stopping

        // ---- tid0: post iter-it partials NOW (max slack before next-iter consume) ----
        if (tid == 0) {
            float Q = 0.f, R = 0.f;
            #pragma unroll
            for (int i = 0; i < 8; ++i) { Q += s_red[i][0]; R += s_red[i][1]; }
            const size_t pb = ((size_t)it * NW + w) * NBLK;
            gpart[(pb + q) * 2 + 0] = (double)Q;
            gpart[(pb + q) * 2 + 1] = (double)R;
            __hip_atomic_fetch_add(&gcnt[it * NW + w], 1u,
                                   __ATOMIC_RELEASE, __HIP_MEMORY_SCOPE_AGENT);
        }

        // ---- K-reduction entirely from LDS (no register carry across barrier) ----
        float a4[4] = {0.f, 0.f, 0.f, 0.f};
        #pragma unroll
        for (int k2 = 0; k2 < 8; ++k2) {
            const float4 p4 = *(const float4*)&s_part[((k2 * RPB + ks) * 64 + kg) * 4];
            a4[0] += p4.x; a4[1] += p4.y; a4[2] += p4.z; a4[3] += p4.w;
        }

        // ---- Adam update ----
        b1p *= 0.9f; b2p *= 0.999f;
        const float bc1 = 1.f - b1p, bc2 = 1.f - b2p;
        #pragma unroll
        for (int j = 0; j < 4; ++j) {
            const float c_ = cf[j];
            const float sgn = (c_ > 0.f) ? 1.f : ((c_ < 0.f) ? -1.f : 0.f);
            const float gg = c1 * (a4[j] - xB[j]) + c2 * sgn;
            m_[j] = 0.9f * m_[j] + 0.1f * gg;
            v_[j] = 0.999f * v_[j] + 0.001f * gg * gg;
            cf[j] = c_ - 1e-3f * (m_[j] / bc1) / (sqrtf(v_[j] / bc2) + 1e-8f);
        }
        *(float4*)&s_cf[(kg >> 3) * SW_S + (kg & 7) * SW_M + ks * 4] =
            make_float4(cf[0], cf[1], cf[2], cf[3]);
        *(float4*)&s_cf2[ks][4 * kg] = make_float4(cf[0], cf[1], cf[2], cf[3]);
    }

    // ---- out[b][k][w], b = q*8+ks, k = 4kg+j ----
    #pragma unroll
    for (int j = 0; j < 4; ++j)
        out[((size_t)(q * RPB + ks) * NB + 4 * kg + j) * NW + w] = cf[j];
}

// ---------------------------------------------------------------------------
extern "C" void kernel_launch(void* const* d_in, const int* in_sizes, int n_in,
                              void* d_out, int out_size, void* d_ws, size_t ws_size,
                              hipStream_t stream)
{
    const float* spec   = (const float*)d_in[0];
    const float* basis  = (const float*)d_in[1];
    const int* p_niter  = (const int*)d_in[2];
    const int* p_pad    = (const int*)d_in[3];
    const int* p_stride = (const int*)d_in[4];
    float* out = (float*)d_out;

    char* ws = (char*)d_ws;
    float*        G     = (float*)ws;                                   // 256 KB
    double*       sxbuf = (double*)(ws + 262144);                       // 2016 B (pad 4 KB)
    double*       gpart = (double*)(ws + 262144 + 4096);                // 193536 B
    unsigned int* gcnt  = (unsigned int*)(ws + 262144 + 4096 + 193536); // (MAXIT*NW+1)*4

    hipMemsetAsync(gcnt, 0, (MAXIT * NW + 1) * sizeof(unsigned int), stream);
    window_kernel<<<dim3(GRID), dim3(512), 0, stream>>>(
        spec, basis, G, p_niter, p_pad, p_stride, sxbuf, gpart, gcnt, out);
}